// Round 3
// 934.966 us; speedup vs baseline: 1.0312x; 1.0312x over previous
//
#include <hip/hip_runtime.h>

typedef unsigned short u16;
typedef unsigned int u32;

typedef short bf16x8 __attribute__((ext_vector_type(8)));
typedef float f32x4 __attribute__((ext_vector_type(4)));
typedef float f32x16 __attribute__((ext_vector_type(16)));

#define T_SEQ 2048
#define MFMA16(a, b, c) __builtin_amdgcn_mfma_f32_16x16x32_bf16(a, b, c, 0, 0, 0)
#define MFMA32(a, b, c) __builtin_amdgcn_mfma_f32_32x32x16_bf16(a, b, c, 0, 0, 0)

__device__ __forceinline__ u16 f2bf(float f) {
    u32 u = __float_as_uint(f);
    u += 0x7fffu + ((u >> 16) & 1u);
    return (u16)(u >> 16);
}
__device__ __forceinline__ float bf2f(u16 s) {
    return __uint_as_float(((u32)s) << 16);
}
__device__ __forceinline__ void g2lds16(const u16* gp, u16* lp) {
    __builtin_amdgcn_global_load_lds((const __attribute__((address_space(1))) void*)gp,
                                     (__attribute__((address_space(3))) void*)lp, 16, 0, 0);
}

// ---------------- cast fp32 -> bf16 ----------------
__global__ __launch_bounds__(256) void cast_f32_bf16(const float* __restrict__ in,
                                                     u16* __restrict__ out, long n) {
    long i = ((long)blockIdx.x * 256 + threadIdx.x) * 4;
    if (i + 3 < n) {
        float4 v = *(const float4*)&in[i];
        out[i + 0] = f2bf(v.x);
        out[i + 1] = f2bf(v.y);
        out[i + 2] = f2bf(v.z);
        out[i + 3] = f2bf(v.w);
    }
}

// ---------------- transpose + cast: [R,C] f32 -> [C,R] bf16 ----------------
__global__ __launch_bounds__(256) void transpose_cast(const float* __restrict__ in,
                                                      u16* __restrict__ out, int R, int C) {
    __shared__ float tile[32][33];
    int c0 = blockIdx.x * 32, r0 = blockIdx.y * 32;
    int tx = threadIdx.x & 31, ty = threadIdx.x >> 5;
#pragma unroll
    for (int rr = 0; rr < 32; rr += 8)
        tile[ty + rr][tx] = in[(long)(r0 + ty + rr) * C + c0 + tx];
    __syncthreads();
#pragma unroll
    for (int rr = 0; rr < 32; rr += 8)
        out[(long)(c0 + ty + rr) * R + r0 + tx] = f2bf(tile[tx][ty + rr]);
}

// ---------------- GEMM: C[M,N] = A[M,K] * BT[N,K], 32x32x16 MFMA, BK=64, XOR-swizzle ------
// (retained for the output projection, MODE 0)
template <int MODE>
__global__ __launch_bounds__(256) void gemm_bt(const u16* __restrict__ A,
                                               const u16* __restrict__ B, void* __restrict__ C,
                                               void* __restrict__ C2, int M, int N, int K, int lda,
                                               int ldb, int ldc) {
    __shared__ __align__(16) u16 As[128 * 64];
    __shared__ __align__(16) u16 Bs[128 * 64];
    int m0 = blockIdx.x * 128, n0 = blockIdx.y * 128;
    int tid = threadIdx.x;
    int lane = tid & 63, w = tid >> 6;
    int wr = w >> 1, wc = w & 1;
    int l31 = lane & 31, hf = lane >> 5;

    f32x16 acc[2][2];
#pragma unroll
    for (int mi = 0; mi < 2; mi++)
#pragma unroll
        for (int nj = 0; nj < 2; nj++)
#pragma unroll
            for (int r = 0; r < 16; r++) acc[mi][nj][r] = 0.f;

    int srow = tid >> 3;
    int sc8 = ((tid & 7) ^ ((tid >> 3) & 7)) * 8;
    const u16* Ag = &A[(long)(m0 + srow) * lda + sc8];
    const u16* Bg = &B[(long)(n0 + srow) * ldb + sc8];

    for (int k0 = 0; k0 < K; k0 += 64) {
#pragma unroll
        for (int p = 0; p < 4; p++) {
            g2lds16(Ag + (long)p * 32 * lda + k0, &As[(p * 256 + tid) * 8]);
            g2lds16(Bg + (long)p * 32 * ldb + k0, &Bs[(p * 256 + tid) * 8]);
        }
        __syncthreads();
#pragma unroll
        for (int ks = 0; ks < 4; ks++) {
            int cell = ((ks * 2 + hf) ^ (l31 & 7)) * 8;
            bf16x8 a0 = *(const bf16x8*)&As[(wr * 64 + l31) * 64 + cell];
            bf16x8 a1 = *(const bf16x8*)&As[(wr * 64 + 32 + l31) * 64 + cell];
            bf16x8 b0 = *(const bf16x8*)&Bs[(wc * 64 + l31) * 64 + cell];
            bf16x8 b1 = *(const bf16x8*)&Bs[(wc * 64 + 32 + l31) * 64 + cell];
            acc[0][0] = MFMA32(a0, b0, acc[0][0]);
            acc[0][1] = MFMA32(a0, b1, acc[0][1]);
            acc[1][0] = MFMA32(a1, b0, acc[1][0]);
            acc[1][1] = MFMA32(a1, b1, acc[1][1]);
        }
        __syncthreads();
    }

    if (MODE == 0) {
#pragma unroll
        for (int mi = 0; mi < 2; mi++)
#pragma unroll
            for (int nj = 0; nj < 2; nj++)
#pragma unroll
                for (int r = 0; r < 16; r++) {
                    int row = m0 + wr * 64 + mi * 32 + (r >> 2) * 8 + hf * 4 + (r & 3);
                    int col = n0 + wc * 64 + nj * 32 + l31;
                    ((float*)C)[(long)row * ldc + col] = acc[mi][nj][r];
                }
    } else {
        u16* dst;
        long dldc;
        int ncol0;
        if (MODE == 2 && n0 >= 8192) {
            dst = (u16*)C2;
            dldc = 4096;
            ncol0 = n0 - 8192;
        } else {
            dst = (u16*)C;
            dldc = (MODE == 2) ? 8192 : ldc;
            ncol0 = n0;
        }
#pragma unroll 1
        for (int half_e = 0; half_e < 2; half_e++) {
            __syncthreads();
            if (wc == half_e) {
#pragma unroll
                for (int mi = 0; mi < 2; mi++)
#pragma unroll
                    for (int nj = 0; nj < 2; nj++)
#pragma unroll
                        for (int r = 0; r < 16; r++) {
                            int row = wr * 64 + mi * 32 + (r >> 2) * 8 + hf * 4 + (r & 3);
                            int col = nj * 32 + l31;
                            u16* base = (row < 64) ? As : Bs;
                            base[(row & 63) * 64 + col] = f2bf(acc[mi][nj][r]);
                        }
            }
            __syncthreads();
#pragma unroll
            for (int rr = 0; rr < 4; rr++) {
                int row = rr * 32 + (tid >> 3), seg = tid & 7;
                u16* base = (row < 64) ? As : Bs;
                *(uint4*)&dst[(long)(m0 + row) * dldc + ncol0 + half_e * 64 + seg * 8] =
                    *(uint4*)&base[(row & 63) * 64 + seg * 8];
            }
        }
    }
}

// ---------------- 256^2 deep-pipelined GEMM for qkvz (bf16 out, qkv/z split) --------------
// A[4096,2048] * B^T[12288,2048]. 8 waves (2Mx4N), BK=32, ring of 4 LDS buffers (128 KiB).
// LDS is FRAGMENT-ORDERED: cell(frag f, lane l) at (f*64+l)*16B -> every ds_read_b128 is
// lane-linear (zero bank conflicts); global_load_lds writes it linearly with the per-lane
// global source pre-swizzled to fragment order (rule 21).
// Schedule per K-step: 2 phases x {ds_read 8|4, stage 2x g2lds16, s_barrier, lgkmcnt(0),
// setprio(1), 16 MFMA, setprio(0), [vmcnt(8)], s_barrier}. vmcnt never drains to 0.
// Safety: iteration i computes buf[i&3], stages K-step i+3 into buf[(i-1)&3] whose reads
// completed before iteration i-1's final barrier; stage issued after that barrier -> no race.
// vmcnt(8) at end of iter i retires the 4 loads of K-step i+1 (FIFO) before iter i+1 reads.
#define VM8 asm volatile("s_waitcnt vmcnt(8)" ::: "memory")
#define VM4 asm volatile("s_waitcnt vmcnt(4)" ::: "memory")
#define VM0 asm volatile("s_waitcnt vmcnt(0)" ::: "memory")
#define VMNONE ((void)0)

#define STAGE_A(S, R2)                       \
    do {                                     \
        u16* Ld = &sbuf[(R2) * 16384];       \
        long ko = (long)(S) * 32;            \
        g2lds16(pA0 + ko, Ld + dA0);         \
        g2lds16(pA1 + ko, Ld + dA1);         \
    } while (0)
#define STAGE_B(S, R2)                          \
    do {                                        \
        u16* Ld = &sbuf[(R2) * 16384 + 8192];   \
        long ko = (long)(S) * 32;               \
        g2lds16(pB0 + ko, Ld + dA0);            \
        g2lds16(pB1 + ko, Ld + dA1);            \
    } while (0)

#define MQUAD(RB, AV)                          \
    acc[RB][0] = MFMA16(AV, b0, acc[RB][0]);   \
    acc[RB][1] = MFMA16(AV, b1, acc[RB][1]);   \
    acc[RB][2] = MFMA16(AV, b2, acc[RB][2]);   \
    acc[RB][3] = MFMA16(AV, b3, acc[RB][3]);

#define GITER(RING, S3, STG, VMSTMT)                                        \
    {                                                                       \
        const u16* LA = &sbuf[(RING) * 16384 + wm8 * 512 + lane8];          \
        const u16* LB = &sbuf[(RING) * 16384 + 8192 + wn4 * 512 + lane8];   \
        bf16x8 b0 = *(const bf16x8*)&LB[0];                                 \
        bf16x8 b1 = *(const bf16x8*)&LB[512];                               \
        bf16x8 b2 = *(const bf16x8*)&LB[1024];                              \
        bf16x8 b3 = *(const bf16x8*)&LB[1536];                              \
        bf16x8 a0 = *(const bf16x8*)&LA[0];                                 \
        bf16x8 a1 = *(const bf16x8*)&LA[512];                               \
        bf16x8 a2 = *(const bf16x8*)&LA[1024];                              \
        bf16x8 a3 = *(const bf16x8*)&LA[1536];                              \
        if (STG) STAGE_A(S3, ((RING) + 3) & 3);                             \
        __builtin_amdgcn_sched_barrier(0);                                  \
        __builtin_amdgcn_s_barrier();                                       \
        asm volatile("s_waitcnt lgkmcnt(0)" ::: "memory");                  \
        __builtin_amdgcn_sched_barrier(0);                                  \
        __builtin_amdgcn_s_setprio(1);                                      \
        MQUAD(0, a0)                                                        \
        MQUAD(1, a1)                                                        \
        MQUAD(2, a2)                                                        \
        MQUAD(3, a3)                                                        \
        __builtin_amdgcn_s_setprio(0);                                      \
        __builtin_amdgcn_s_barrier();                                       \
        a0 = *(const bf16x8*)&LA[2048];                                     \
        a1 = *(const bf16x8*)&LA[2560];                                     \
        a2 = *(const bf16x8*)&LA[3072];                                     \
        a3 = *(const bf16x8*)&LA[3584];                                     \
        if (STG) STAGE_B(S3, ((RING) + 3) & 3);                             \
        __builtin_amdgcn_sched_barrier(0);                                  \
        __builtin_amdgcn_s_barrier();                                       \
        asm volatile("s_waitcnt lgkmcnt(0)" ::: "memory");                  \
        __builtin_amdgcn_sched_barrier(0);                                  \
        __builtin_amdgcn_s_setprio(1);                                      \
        MQUAD(4, a0)                                                        \
        MQUAD(5, a1)                                                        \
        MQUAD(6, a2)                                                        \
        MQUAD(7, a3)                                                        \
        __builtin_amdgcn_s_setprio(0);                                      \
        VMSTMT;                                                             \
        __builtin_amdgcn_s_barrier();                                       \
    }

__global__ __launch_bounds__(512, 2) void gemm256(const u16* __restrict__ A,
                                                  const u16* __restrict__ B,
                                                  u16* __restrict__ Cq, u16* __restrict__ Cz) {
    __shared__ __align__(16) u16 sbuf[65536];  // 128 KiB: 4 rings x (A 8192 + B 8192 u16)
    int bid = blockIdx.x;
    int swz = (bid & 7) * 96 + (bid >> 3);  // bijective XCD swizzle, 768 = 8*96
    int m0 = (swz & 15) * 256;              // M=4096 -> 16 m-tiles (fastest: share B panel)
    int n0 = (swz >> 4) * 256;              // N=12288 -> 48 n-tiles
    int tid = threadIdx.x;
    int lane = tid & 63, w = tid >> 6;
    int l15 = lane & 15, quad = lane >> 4;
    int wm8 = (w >> 2) * 8, wn4 = (w & 3) * 4;
    int lane8 = lane * 8;
    // staging: wave w covers fragments w (j=0) and 8+w (j=1) of each operand
    int dA0 = w * 512 + lane8, dA1 = w * 512 + lane8 + 4096;
    const u16* pA0 = &A[(long)(m0 + w * 16 + l15) * 2048 + quad * 8];
    const u16* pA1 = pA0 + 128L * 2048;
    const u16* pB0 = &B[(long)(n0 + w * 16 + l15) * 2048 + quad * 8];
    const u16* pB1 = pB0 + 128L * 2048;

    f32x4 acc[8][4];
#pragma unroll
    for (int i = 0; i < 8; i++)
#pragma unroll
        for (int j = 0; j < 4; j++) acc[i][j] = (f32x4){0.f, 0.f, 0.f, 0.f};

    // prologue: stage K-steps 0,1,2 (12 loads); wait until K-step 0 landed (8 outstanding)
    STAGE_A(0, 0);
    STAGE_B(0, 0);
    STAGE_A(1, 1);
    STAGE_B(1, 1);
    STAGE_A(2, 2);
    STAGE_B(2, 2);
    VM8;
    __builtin_amdgcn_s_barrier();

    for (int it = 0; it < 60; it += 4) {
        GITER(0, it + 3, 1, VM8);
        GITER(1, it + 4, 1, VM8);
        GITER(2, it + 5, 1, VM8);
        GITER(3, it + 6, 1, VM8);
    }
    GITER(0, 63, 1, VM8);   // i=60
    GITER(1, 0, 0, VM4);    // i=61: outstanding {62,63}=8, retire 62
    GITER(2, 0, 0, VM0);    // i=62: retire 63
    GITER(3, 0, 0, VMNONE); // i=63

    // epilogue: acc -> LDS bf16 [256][256] with 32B-granule XOR swizzle, then coalesced store
#pragma unroll
    for (int rb = 0; rb < 8; rb++)
#pragma unroll
        for (int cb = 0; cb < 4; cb++)
#pragma unroll
            for (int r = 0; r < 4; r++) {
                int row = wm8 * 16 + rb * 16 + quad * 4 + r;
                int col = wn4 * 16 + cb * 16 + l15;
                int cg = col >> 4;
                int phys = row * 256 + ((cg ^ (row & 7)) << 4) + (col & 15);
                sbuf[phys] = f2bf(acc[rb][cb][r]);
            }
    __syncthreads();
    u16* dst;
    long dldc;
    int ncol0;
    if (n0 >= 8192) {
        dst = Cz;
        dldc = 4096;
        ncol0 = n0 - 8192;
    } else {
        dst = Cq;
        dldc = 8192;
        ncol0 = n0;
    }
#pragma unroll
    for (int p = 0; p < 16; p++) {
        int row = p * 16 + (tid >> 5);
        int seg = tid & 31;
        int cg = seg >> 1;
        int phys = row * 256 + ((cg ^ (row & 7)) << 4) + (seg & 1) * 8;
        *(uint4*)&dst[(long)(m0 + row) * dldc + ncol0 + seg * 8] = *(const uint4*)&sbuf[phys];
    }
}

// ---------------- ba = hidden @ W_ba -> g, beta (MFMA, padded LDS) ----------------
__global__ __launch_bounds__(256) void ba_gemm(const u16* __restrict__ hid,
                                               const u16* __restrict__ WbaT,
                                               const float* __restrict__ A_log,
                                               const float* __restrict__ dt_bias,
                                               float* __restrict__ g, float* __restrict__ beta) {
    __shared__ __align__(16) u16 As2[32 * 40];
    __shared__ __align__(16) u16 Bs2[64 * 40];
    int m0 = blockIdx.x * 32;
    int tid = threadIdx.x, lane = tid & 63, w = tid >> 6;
    int quad = lane >> 4, l15 = lane & 15;
    int trow = w & 1;
    int ctile = (w >> 1) * 2;
    f32x4 acc[2];
    acc[0] = (f32x4){0.f, 0.f, 0.f, 0.f};
    acc[1] = (f32x4){0.f, 0.f, 0.f, 0.f};
    int srow = tid >> 2, sc8 = (tid & 3) * 8;
    for (int k0 = 0; k0 < 2048; k0 += 32) {
        if (tid < 128)
            *(uint4*)&As2[srow * 40 + sc8] =
                *(const uint4*)&hid[(long)(m0 + srow) * 2048 + k0 + sc8];
        *(uint4*)&Bs2[srow * 40 + sc8] = *(const uint4*)&WbaT[(long)srow * 2048 + k0 + sc8];
        __syncthreads();
        bf16x8 a = *(const bf16x8*)&As2[(trow * 16 + l15) * 40 + quad * 8];
#pragma unroll
        for (int j = 0; j < 2; j++) {
            bf16x8 b = *(const bf16x8*)&Bs2[((ctile + j) * 16 + l15) * 40 + quad * 8];
            acc[j] = MFMA16(a, b, acc[j]);
        }
        __syncthreads();
    }
#pragma unroll
    for (int j = 0; j < 2; j++)
#pragma unroll
        for (int r = 0; r < 4; r++) {
            int tok = m0 + trow * 16 + quad * 4 + r;
            int col = (ctile + j) * 16 + l15;
            float tot = acc[j][r];
            if (col < 32) {
                beta[(long)tok * 32 + col] = 1.f / (1.f + expf(-tot));
            } else {
                int h = col - 32;
                float x = tot + dt_bias[h];
                float sp = (x > 20.f) ? x : log1pf(expf(x));
                g[(long)tok * 32 + h] = -expf(A_log[h]) * sp;
            }
        }
}

// ---------------- causal conv + SiLU + l2norm + split (coalesced, LDS) ----------------
__global__ __launch_bounds__(256) void conv_gate(const u16* __restrict__ qkv,
                                                 const float* __restrict__ conv_w,
                                                 u16* __restrict__ qn, u16* __restrict__ kn,
                                                 u16* __restrict__ vc) {
    int tok = blockIdx.x, tid = threadIdx.x;
    int tloc = tok & (T_SEQ - 1);
    __shared__ float mixed[8192];
    __shared__ float sh_norm[32];
    uint4 zero4;
    zero4.x = zero4.y = zero4.z = zero4.w = 0u;
#pragma unroll
    for (int i = 0; i < 4; i++) {
        int c = (i * 256 + tid) * 8;
        long base = (long)tok * 8192 + c;
        uint4 x3 = *(const uint4*)&qkv[base];
        uint4 x2 = (tloc >= 1) ? *(const uint4*)&qkv[base - 8192] : zero4;
        uint4 x1 = (tloc >= 2) ? *(const uint4*)&qkv[base - 16384] : zero4;
        uint4 x0 = (tloc >= 3) ? *(const uint4*)&qkv[base - 24576] : zero4;
        const u16* p0 = (const u16*)&x0;
        const u16* p1 = (const u16*)&x1;
        const u16* p2 = (const u16*)&x2;
        const u16* p3 = (const u16*)&x3;
#pragma unroll
        for (int e = 0; e < 8; e++) {
            float4 wv = *(const float4*)&conv_w[(long)(c + e) * 4];
            float a = bf2f(p0[e]) * wv.x + bf2f(p1[e]) * wv.y + bf2f(p2[e]) * wv.z +
                      bf2f(p3[e]) * wv.w;
            mixed[c + e] = a / (1.f + __expf(-a));
        }
    }
    __syncthreads();
    int grp = tid >> 3, sub = tid & 7;
    float ss = 0.f;
#pragma unroll
    for (int e = 0; e < 16; e++) {
        float v = mixed[grp * 128 + sub * 16 + e];
        ss += v * v;
    }
    ss += __shfl_xor(ss, 4, 8);
    ss += __shfl_xor(ss, 2, 8);
    ss += __shfl_xor(ss, 1, 8);
    if (sub == 0) sh_norm[grp] = rsqrtf(ss + 1e-6f);
    __syncthreads();
#pragma unroll
    for (int i = 0; i < 4; i++) {
        int c = (i * 256 + tid) * 8;
        float nf = (c < 2048) ? sh_norm[c >> 7] * 0.08838834764831845f
                              : ((c < 4096) ? sh_norm[c >> 7] : 1.f);
        u16 ob[8];
#pragma unroll
        for (int e = 0; e < 8; e++) ob[e] = f2bf(mixed[c + e] * nf);
        uint4 val = *(uint4*)ob;
        if (c < 2048)
            *(uint4*)&qn[(long)tok * 2048 + c] = val;
        else if (c < 4096)
            *(uint4*)&kn[(long)tok * 2048 + (c - 2048)] = val;
        else
            *(uint4*)&vc[(long)tok * 4096 + (c - 4096)] = val;
    }
}

// ---------------- phase A: per-chunk WY transform (padded LDS, YT transposed) ----------
__global__ __launch_bounds__(256) void phaseA(const u16* __restrict__ qn,
                                              const u16* __restrict__ kn,
                                              const u16* __restrict__ vc,
                                              const float* __restrict__ g,
                                              const float* __restrict__ beta,
                                              u16* __restrict__ Tv_g, u16* __restrict__ Tw_g,
                                              u16* __restrict__ Q2_g, u16* __restrict__ obuf) {
    __shared__ __align__(16) u16 kbuf[64][136];  // k tile (padded); later L at stride 72
    __shared__ __align__(16) float BMt[64][68];  // BMt[j][i] (padded)
    __shared__ __align__(16) u16 YT[256][72];    // Y^T: row=col(0..127 V / 128..255 W), col=token
    u16* Lbf = &kbuf[0][0];

    int bid = blockIdx.x;
    int c = bid & 31, h = (bid >> 5) & 31, b = bid >> 10;
    int hk = h >> 1;
    long tokbase = (long)b * T_SEQ + c * 64;
    long cb = (long)bid * 8192;
    int tid = threadIdx.x, lane = tid & 63, w = tid >> 6;
    int quad = lane >> 4, l15 = lane & 15;

    float gl = g[(tokbase + lane) * 32 + h];
    float bl = beta[(tokbase + lane) * 32 + h];
    float cgl = gl;
#pragma unroll
    for (int d = 1; d < 64; d <<= 1) {
        float y = __shfl_up(cgl, d);
        if (lane >= d) cgl += y;
    }
    float wscl = bl * __expf(cgl);
    float eCgl = __expf(cgl);

#pragma unroll
    for (int p = 0; p < 4; p++) {
        int u = p * 256 + tid;
        int row = u >> 4, col8 = (u & 15) * 8;
        *(uint4*)&kbuf[row][col8] = *(const uint4*)&kn[(tokbase + row) * 2048 + hk * 128 + col8];
    }
    __syncthreads();

    // Gram_kk -> BMt
    {
        f32x4 gk[4];
#pragma unroll
        for (int nj = 0; nj < 4; nj++) gk[nj] = (f32x4){0.f, 0.f, 0.f, 0.f};
#pragma unroll
        for (int kk = 0; kk < 4; kk++) {
            bf16x8 a = *(const bf16x8*)&kbuf[w * 16 + l15][kk * 32 + quad * 8];
#pragma unroll
            for (int nj = 0; nj < 4; nj++) {
                bf16x8 bb = *(const bf16x8*)&kbuf[nj * 16 + l15][kk * 32 + quad * 8];
                gk[nj] = MFMA16(a, bb, gk[nj]);
            }
        }
#pragma unroll
        for (int nj = 0; nj < 4; nj++)
#pragma unroll
            for (int r = 0; r < 4; r++) {
                int i = w * 16 + quad * 4 + r;
                int j = nj * 16 + l15;
                float cgi = __shfl(cgl, i), cgj = __shfl(cgl, j);
                float bi = __shfl(bl, i);
                BMt[j][i] = (j < i) ? bi * gk[nj][r] * __expf(cgi - cgj) : 0.f;
            }
    }
    __syncthreads();

    // blocked forward substitution: (I+BM) Y = B*[V | W] ; Y^T into YT
    {
        int col = tid;
        bool isV = col < 128;
        int kcol = col & 127;
        long vbase = tokbase * 4096 + h * 128 + kcol;
        float Yreg[8], acc8[8];
#pragma unroll 1
        for (int bi = 0; bi < 8; ++bi) {
            float vr[8];
            if (isV) {
#pragma unroll
                for (int ii = 0; ii < 8; ii++)
                    vr[ii] = bf2f(vc[vbase + (long)(bi * 8 + ii) * 4096]);
            }
#pragma unroll
            for (int ii = 0; ii < 8; ii++) acc8[ii] = 0.f;
            for (int j = 0; j < bi * 8; ++j) {
                float yv = bf2f(YT[col][j]);
                float4 m0 = *(const float4*)&BMt[j][bi * 8];
                float4 m1 = *(const float4*)&BMt[j][bi * 8 + 4];
                acc8[0] += m0.x * yv;
                acc8[1] += m0.y * yv;
                acc8[2] += m0.z * yv;
                acc8[3] += m0.w * yv;
                acc8[4] += m1.x * yv;
                acc8[5] += m1.y * yv;
                acc8[6] += m1.z * yv;
                acc8[7] += m1.w * yv;
            }
            u16 outb[8];
#pragma unroll
            for (int ii = 0; ii < 8; ii++) {
                int i = bi * 8 + ii;
                float rhs = isV ? __shfl(bl, i) * vr[ii] : __shfl(wscl, i) * bf2f(kbuf[i][kcol]);
                float s = rhs - acc8[ii];
#pragma unroll
                for (int jj = 0; jj < 8; jj++)
                    if (jj < ii) s -= BMt[bi * 8 + jj][i] * Yreg[jj];
                Yreg[ii] = s;
                outb[ii] = f2bf(s);
            }
            *(uint4*)&YT[col][bi * 8] = *(uint4*)outb;
#pragma unroll
            for (int ii = 0; ii < 8; ii++) {
                if (isV)
                    Tv_g[cb + (bi * 8 + ii) * 128 + kcol] = outb[ii];
                else
                    Tw_g[cb + (bi * 8 + ii) * 128 + kcol] = outb[ii];
            }
        }
    }
    __syncthreads();

    // Gram_qk -> L (bf16, stride 72, overlays kbuf)
    {
        f32x4 qk_[4];
#pragma unroll
        for (int nj = 0; nj < 4; nj++) qk_[nj] = (f32x4){0.f, 0.f, 0.f, 0.f};
#pragma unroll
        for (int kk = 0; kk < 4; kk++) {
            bf16x8 a = *(const bf16x8*)&qn[(tokbase + w * 16 + l15) * 2048 + hk * 128 + kk * 32 +
                                           quad * 8];
#pragma unroll
            for (int nj = 0; nj < 4; nj++) {
                bf16x8 bb = *(const bf16x8*)&kbuf[nj * 16 + l15][kk * 32 + quad * 8];
                qk_[nj] = MFMA16(a, bb, qk_[nj]);
            }
        }
        __syncthreads();  // all kbuf reads done before Lbf overwrite
#pragma unroll
        for (int nj = 0; nj < 4; nj++)
#pragma unroll
            for (int r = 0; r < 4; r++) {
                int t = w * 16 + quad * 4 + r;
                int rr = nj * 16 + l15;
                float cgt = __shfl(cgl, t), cgr = __shfl(cgl, rr);
                float val = (rr <= t) ? qk_[nj][r] * __expf(cgt - cgr) : 0.f;
                Lbf[t * 72 + rr] = f2bf(val);
            }
    }
    __syncthreads();

    // O_loc = L*Tv -> obuf ; Q2 = Qtilde - L*Tw   (A=Lbf b128, B=YT b128)
#pragma unroll 1
    for (int half = 0; half < 2; half++) {
        f32x4 oa[8];
#pragma unroll
        for (int nj = 0; nj < 8; nj++) oa[nj] = (f32x4){0.f, 0.f, 0.f, 0.f};
#pragma unroll
        for (int kk = 0; kk < 2; kk++) {
            bf16x8 a = *(const bf16x8*)&Lbf[(w * 16 + l15) * 72 + kk * 32 + quad * 8];
#pragma unroll
            for (int nj = 0; nj < 8; nj++) {
                bf16x8 bb = *(const bf16x8*)&YT[half * 128 + nj * 16 + l15][kk * 32 + quad * 8];
                oa[nj] = MFMA16(a, bb, oa[nj]);
            }
        }
        if (half == 0) {
#pragma unroll
            for (int nj = 0; nj < 8; nj++)
#pragma unroll
                for (int r = 0; r < 4; r++) {
                    int t = w * 16 + quad * 4 + r;
                    int vcol = nj * 16 + l15;
                    obuf[(tokbase + t) * 4096 + h * 128 + vcol] = f2bf(oa[nj][r]);
                }
        } else {
#pragma unroll
            for (int nj = 0; nj < 8; nj++)
#pragma unroll
                for (int r = 0; r < 4; r++) {
                    int t = w * 16 + quad * 4 + r;
                    int kcol = nj * 16 + l15;
                    float qsc = __shfl(eCgl, t);
                    float qv = bf2f(qn[(tokbase + t) * 2048 + hk * 128 + kcol]);
                    Q2_g[cb + t * 128 + kcol] = f2bf(qsc * qv - oa[nj][r]);
                }
        }
    }
}

// ---------------- phase B: sequential chunk recurrence, software-pipelined ----------------
__global__ __launch_bounds__(256) void phaseB(const u16* __restrict__ kn,
                                              const float* __restrict__ g,
                                              const u16* __restrict__ Tv_g,
                                              const u16* __restrict__ Tw_g,
                                              const u16* __restrict__ Q2_g,
                                              u16* __restrict__ obuf) {
    __shared__ __align__(16) float Sf[128][32];
    __shared__ __align__(16) u16 SbfT[32][136];
    __shared__ __align__(16) u16 KhT[128][72];
    __shared__ __align__(16) u16 Ut[32][72];

    int bid = blockIdx.x;
    int vq = bid & 3, h = (bid >> 2) & 31, b = bid >> 7;
    int hk = h >> 1;
    int tid = threadIdx.x, lane = tid & 63, w = tid >> 6;
    int quad = lane >> 4, l15 = lane & 15;

    for (int p = tid; p < 128 * 32; p += 256) ((float*)Sf)[p] = 0.f;
    for (int p = tid; p < 32 * 136; p += 256) ((u16*)SbfT)[p] = 0;
    __syncthreads();

    float gl_pf;
    uint4 kreg[4];
    bf16x8 aTw[4], aQ2[4];
    u16 tvv_pf[2][4], oold[2][4];

#define PB_PREFETCH(cc)                                                                      \
    {                                                                                        \
        long tb_ = (long)b * T_SEQ + (cc) * 64;                                              \
        long cb_ = ((long)((b * 32 + h) * 32) + (cc)) * 8192;                                \
        gl_pf = g[(tb_ + lane) * 32 + h];                                                    \
        const u16* kp_ = &kn[(tb_ + lane) * 2048 + hk * 128 + w * 32];                       \
        kreg[0] = *(const uint4*)&kp_[0];                                                    \
        kreg[1] = *(const uint4*)&kp_[8];                                                    \
        kreg[2] = *(const uint4*)&kp_[16];                                                   \
        kreg[3] = *(const uint4*)&kp_[24];                                                   \
        _Pragma("unroll") for (int kk = 0; kk < 4; kk++) {                                   \
            aTw[kk] = *(const bf16x8*)&Tw_g[cb_ + (w * 16 + l15) * 128 + kk * 32 + quad * 8]; \
            aQ2[kk] = *(const bf16x8*)&Q2_g[cb_ + (w * 16 + l15) * 128 + kk * 32 + quad * 8]; \
        }                                                                                    \
        _Pragma("unroll") for (int nj = 0; nj < 2; nj++) _Pragma("unroll")                   \
            for (int r = 0; r < 4; r++) {                                                    \
            int i_ = w * 16 + quad * 4 + r;                                                  \
            int vg_ = vq * 32 + nj * 16 + l15;                                               \
            tvv_pf[nj][r] = Tv_g[cb_ + (long)i_ * 128 + vg_];                                \
            oold[nj][r] = obuf[(tb_ + i_) * 4096 + h * 128 + vg_];                           \
        }                                                                                    \
    }

    PB_PREFETCH(0);

    for (int c = 0; c < 32; ++c) {
        long tokbase = (long)b * T_SEQ + c * 64;
        float cgl = gl_pf;
#pragma unroll
        for (int d = 1; d < 64; d <<= 1) {
            float y = __shfl_up(cgl, d);
            if (lane >= d) cgl += y;
        }
        float cgC = __shfl(cgl, 63);
        float A_C = __expf(cgC);
        float kscl = __expf(cgC - cgl);

        {
            const u16* kk16 = (const u16*)kreg;
#pragma unroll
            for (int j = 0; j < 32; j++) KhT[w * 32 + j][lane] = f2bf(bf2f(kk16[j]) * kscl);
        }

        f32x4 y1[2], oo[2];
#pragma unroll
        for (int nj = 0; nj < 2; nj++) {
            y1[nj] = (f32x4){0.f, 0.f, 0.f, 0.f};
            oo[nj] = (f32x4){0.f, 0.f, 0.f, 0.f};
        }
#pragma unroll
        for (int kk = 0; kk < 4; kk++) {
#pragma unroll
            for (int nj = 0; nj < 2; nj++) {
                bf16x8 bb = *(const bf16x8*)&SbfT[nj * 16 + l15][kk * 32 + quad * 8];
                y1[nj] = MFMA16(aTw[kk], bb, y1[nj]);
                oo[nj] = MFMA16(aQ2[kk], bb, oo[nj]);
            }
        }
#pragma unroll
        for (int nj = 0; nj < 2; nj++)
#pragma unroll
            for (int r = 0; r < 4; r++) {
                int i = w * 16 + quad * 4 + r;
                int vl = nj * 16 + l15;
                int vg = vq * 32 + vl;
                Ut[vl][i] = f2bf(bf2f(tvv_pf[nj][r]) - y1[nj][r]);
                obuf[(tokbase + i) * 4096 + h * 128 + vg] = f2bf(bf2f(oold[nj][r]) + oo[nj][r]);
            }
        __syncthreads();

        if (c + 1 < 32) PB_PREFETCH(c + 1);

#pragma unroll
        for (int mm = 0; mm < 2; mm++) {
            int mi = 2 * w + mm;
#pragma unroll
            for (int nj = 0; nj < 2; nj++) {
                f32x4 sacc;
#pragma unroll
                for (int r = 0; r < 4; r++)
                    sacc[r] = A_C * Sf[mi * 16 + quad * 4 + r][nj * 16 + l15];
#pragma unroll
                for (int kk = 0; kk < 2; kk++) {
                    bf16x8 a = *(const bf16x8*)&KhT[mi * 16 + l15][kk * 32 + quad * 8];
                    bf16x8 bb = *(const bf16x8*)&Ut[nj * 16 + l15][kk * 32 + quad * 8];
                    sacc = MFMA16(a, bb, sacc);
                }
#pragma unroll
                for (int r = 0; r < 4; r++) {
                    int kd = mi * 16 + quad * 4 + r, vl = nj * 16 + l15;
                    Sf[kd][vl] = sacc[r];
                    SbfT[vl][kd] = f2bf(sacc[r]);
                }
            }
        }
        __syncthreads();
    }
#undef PB_PREFETCH
}

// ---------------- gated RMSNorm ----------------
__global__ __launch_bounds__(256) void gated_norm(const u16* __restrict__ obuf,
                                                  const u16* __restrict__ zbuf,
                                                  const float* __restrict__ norm_w,
                                                  u16* __restrict__ xn) {
    int tok = blockIdx.x, tid = threadIdx.x;
    long obase = (long)tok * 4096 + tid * 16;
    u16 ob[16], zb[16];
    *(uint4*)(ob + 0) = *(const uint4*)&obuf[obase];
    *(uint4*)(ob + 8) = *(const uint4*)&obuf[obase + 8];
    *(uint4*)(zb + 0) = *(const uint4*)&zbuf[obase];
    *(uint4*)(zb + 8) = *(const uint4*)&zbuf[obase + 8];
    float x[16];
    float ss = 0.f;
#pragma unroll
    for (int i = 0; i < 16; i++) {
        float ov = bf2f(ob[i]);
        float zv = bf2f(zb[i]);
        float xv = ov * (zv / (1.f + expf(-zv)));
        x[i] = xv;
        ss += xv * xv;
    }
    ss += __shfl_xor(ss, 4, 8);
    ss += __shfl_xor(ss, 2, 8);
    ss += __shfl_xor(ss, 1, 8);
    float scale = rsqrtf(ss * (1.f / 128.f) + 1e-6f);
    int cbase = (tid * 16) & 127;
#pragma unroll
    for (int i = 0; i < 16; i++)
        xn[(long)tok * 4096 + tid * 16 + i] = f2bf(x[i] * scale * (1.f + norm_w[cbase + i]));
}

// ---------------- launch ----------------
extern "C" void kernel_launch(void* const* d_in, const int* in_sizes, int n_in, void* d_out,
                              int out_size, void* d_ws, size_t ws_size, hipStream_t stream) {
    const float* hidden = (const float*)d_in[0];
    const float* W_qkvz = (const float*)d_in[1];
    const float* W_ba = (const float*)d_in[2];
    const float* conv_w = (const float*)d_in[3];
    const float* A_log = (const float*)d_in[4];
    const float* dt_bias = (const float*)d_in[5];
    const float* norm_w = (const float*)d_in[6];
    const float* W_out = (const float*)d_in[7];
    float* out = (float*)d_out;

    char* ws = (char*)d_ws;
    u16* wqT = (u16*)(ws + 0);
    u16* qn = (u16*)(ws + 0);
    u16* vc = (u16*)(ws + 16777216L);
    u16* hidbf = (u16*)(ws + 50331648L);
    u16* kn = (u16*)(ws + 50331648L);
    u16* woT = (u16*)(ws + 67108864L);
    u16* qkv_raw = (u16*)(ws + 83886080L);
    u16* Tv = (u16*)(ws + 83886080L);
    u16* Tw = (u16*)(ws + 117440512L);
    u16* xn = (u16*)(ws + 83886080L);
    u16* WbaT = (u16*)(ws + 150994944L);
    u16* zbuf = (u16*)(ws + 150994944L);
    u16* Q2 = (u16*)(ws + 184549376L);
    float* g = (float*)(ws + 218103808L);
    float* beta = (float*)(ws + 218628096L);
    u16* obuf = vc;

    cast_f32_bf16<<<8192, 256, 0, stream>>>(hidden, hidbf, 8388608L);
    transpose_cast<<<dim3(384, 64), 256, 0, stream>>>(W_qkvz, wqT, 2048, 12288);
    transpose_cast<<<dim3(64, 128), 256, 0, stream>>>(W_out, woT, 4096, 2048);
    transpose_cast<<<dim3(2, 64), 256, 0, stream>>>(W_ba, WbaT, 2048, 64);
    ba_gemm<<<128, 256, 0, stream>>>(hidbf, WbaT, A_log, dt_bias, g, beta);
    gemm256<<<768, 512, 0, stream>>>(hidbf, wqT, qkv_raw, zbuf);
    conv_gate<<<4096, 256, 0, stream>>>(qkv_raw, conv_w, qn, kn, vc);
    phaseA<<<2048, 256, 0, stream>>>(qn, kn, vc, g, beta, Tv, Tw, Q2, obuf);
    phaseB<<<256, 256, 0, stream>>>(kn, g, Tv, Tw, Q2, obuf);
    gated_norm<<<4096, 256, 0, stream>>>(obuf, zbuf, norm_w, xn);
    gemm_bt<0><<<dim3(32, 16), 256, 0, stream>>>(xn, woT, out, nullptr, 4096, 2048, 4096, 4096,
                                                 4096, 2048);
}

// Round 4
// 934.334 us; speedup vs baseline: 1.0319x; 1.0007x over previous
//
#include <hip/hip_runtime.h>

typedef unsigned short u16;
typedef unsigned int u32;

typedef short bf16x8 __attribute__((ext_vector_type(8)));
typedef float f32x4 __attribute__((ext_vector_type(4)));
typedef float f32x16 __attribute__((ext_vector_type(16)));

#define T_SEQ 2048
#define MFMA16(a, b, c) __builtin_amdgcn_mfma_f32_16x16x32_bf16(a, b, c, 0, 0, 0)
#define MFMA32(a, b, c) __builtin_amdgcn_mfma_f32_32x32x16_bf16(a, b, c, 0, 0, 0)

__device__ __forceinline__ u16 f2bf(float f) {
    u32 u = __float_as_uint(f);
    u += 0x7fffu + ((u >> 16) & 1u);
    return (u16)(u >> 16);
}
__device__ __forceinline__ float bf2f(u16 s) {
    return __uint_as_float(((u32)s) << 16);
}
__device__ __forceinline__ void g2lds16(const u16* gp, u16* lp) {
    __builtin_amdgcn_global_load_lds((const __attribute__((address_space(1))) void*)gp,
                                     (__attribute__((address_space(3))) void*)lp, 16, 0, 0);
}

// ---------------- cast fp32 -> bf16 ----------------
__global__ __launch_bounds__(256) void cast_f32_bf16(const float* __restrict__ in,
                                                     u16* __restrict__ out, long n) {
    long i = ((long)blockIdx.x * 256 + threadIdx.x) * 4;
    if (i + 3 < n) {
        float4 v = *(const float4*)&in[i];
        out[i + 0] = f2bf(v.x);
        out[i + 1] = f2bf(v.y);
        out[i + 2] = f2bf(v.z);
        out[i + 3] = f2bf(v.w);
    }
}

// ---------------- transpose + cast: [R,C] f32 -> [C,R] bf16 ----------------
__global__ __launch_bounds__(256) void transpose_cast(const float* __restrict__ in,
                                                      u16* __restrict__ out, int R, int C) {
    __shared__ float tile[32][33];
    int c0 = blockIdx.x * 32, r0 = blockIdx.y * 32;
    int tx = threadIdx.x & 31, ty = threadIdx.x >> 5;
#pragma unroll
    for (int rr = 0; rr < 32; rr += 8)
        tile[ty + rr][tx] = in[(long)(r0 + ty + rr) * C + c0 + tx];
    __syncthreads();
#pragma unroll
    for (int rr = 0; rr < 32; rr += 8)
        out[(long)(c0 + ty + rr) * R + r0 + tx] = f2bf(tile[tx][ty + rr]);
}

// ---------------- GEMM: C[M,N] = A[M,K] * BT[N,K], 32x32x16 MFMA, BK=64, XOR-swizzle ------
// (retained for the output projection, MODE 0)
template <int MODE>
__global__ __launch_bounds__(256) void gemm_bt(const u16* __restrict__ A,
                                               const u16* __restrict__ B, void* __restrict__ C,
                                               void* __restrict__ C2, int M, int N, int K, int lda,
                                               int ldb, int ldc) {
    __shared__ __align__(16) u16 As[128 * 64];
    __shared__ __align__(16) u16 Bs[128 * 64];
    int m0 = blockIdx.x * 128, n0 = blockIdx.y * 128;
    int tid = threadIdx.x;
    int lane = tid & 63, w = tid >> 6;
    int wr = w >> 1, wc = w & 1;
    int l31 = lane & 31, hf = lane >> 5;

    f32x16 acc[2][2];
#pragma unroll
    for (int mi = 0; mi < 2; mi++)
#pragma unroll
        for (int nj = 0; nj < 2; nj++)
#pragma unroll
            for (int r = 0; r < 16; r++) acc[mi][nj][r] = 0.f;

    int srow = tid >> 3;
    int sc8 = ((tid & 7) ^ ((tid >> 3) & 7)) * 8;
    const u16* Ag = &A[(long)(m0 + srow) * lda + sc8];
    const u16* Bg = &B[(long)(n0 + srow) * ldb + sc8];

    for (int k0 = 0; k0 < K; k0 += 64) {
#pragma unroll
        for (int p = 0; p < 4; p++) {
            g2lds16(Ag + (long)p * 32 * lda + k0, &As[(p * 256 + tid) * 8]);
            g2lds16(Bg + (long)p * 32 * ldb + k0, &Bs[(p * 256 + tid) * 8]);
        }
        __syncthreads();
#pragma unroll
        for (int ks = 0; ks < 4; ks++) {
            int cell = ((ks * 2 + hf) ^ (l31 & 7)) * 8;
            bf16x8 a0 = *(const bf16x8*)&As[(wr * 64 + l31) * 64 + cell];
            bf16x8 a1 = *(const bf16x8*)&As[(wr * 64 + 32 + l31) * 64 + cell];
            bf16x8 b0 = *(const bf16x8*)&Bs[(wc * 64 + l31) * 64 + cell];
            bf16x8 b1 = *(const bf16x8*)&Bs[(wc * 64 + 32 + l31) * 64 + cell];
            acc[0][0] = MFMA32(a0, b0, acc[0][0]);
            acc[0][1] = MFMA32(a0, b1, acc[0][1]);
            acc[1][0] = MFMA32(a1, b0, acc[1][0]);
            acc[1][1] = MFMA32(a1, b1, acc[1][1]);
        }
        __syncthreads();
    }

    if (MODE == 0) {
#pragma unroll
        for (int mi = 0; mi < 2; mi++)
#pragma unroll
            for (int nj = 0; nj < 2; nj++)
#pragma unroll
                for (int r = 0; r < 16; r++) {
                    int row = m0 + wr * 64 + mi * 32 + (r >> 2) * 8 + hf * 4 + (r & 3);
                    int col = n0 + wc * 64 + nj * 32 + l31;
                    ((float*)C)[(long)row * ldc + col] = acc[mi][nj][r];
                }
    } else {
        u16* dst;
        long dldc;
        int ncol0;
        if (MODE == 2 && n0 >= 8192) {
            dst = (u16*)C2;
            dldc = 4096;
            ncol0 = n0 - 8192;
        } else {
            dst = (u16*)C;
            dldc = (MODE == 2) ? 8192 : ldc;
            ncol0 = n0;
        }
#pragma unroll 1
        for (int half_e = 0; half_e < 2; half_e++) {
            __syncthreads();
            if (wc == half_e) {
#pragma unroll
                for (int mi = 0; mi < 2; mi++)
#pragma unroll
                    for (int nj = 0; nj < 2; nj++)
#pragma unroll
                        for (int r = 0; r < 16; r++) {
                            int row = wr * 64 + mi * 32 + (r >> 2) * 8 + hf * 4 + (r & 3);
                            int col = nj * 32 + l31;
                            u16* base = (row < 64) ? As : Bs;
                            base[(row & 63) * 64 + col] = f2bf(acc[mi][nj][r]);
                        }
            }
            __syncthreads();
#pragma unroll
            for (int rr = 0; rr < 4; rr++) {
                int row = rr * 32 + (tid >> 3), seg = tid & 7;
                u16* base = (row < 64) ? As : Bs;
                *(uint4*)&dst[(long)(m0 + row) * dldc + ncol0 + half_e * 64 + seg * 8] =
                    *(uint4*)&base[(row & 63) * 64 + seg * 8];
            }
        }
    }
}

// ---------------- 256^2 deep-pipelined GEMM for qkvz (bf16 out, qkv/z split) --------------
// A[4096,2048] * B^T[12288,2048]. 8 waves (2Mx4N), BK=32, ring of 4 LDS buffers (128 KiB).
// LDS is FRAGMENT-ORDERED (lane-linear 16B cells) -> all ds_read_b128 conflict-free;
// global_load_lds writes linearly with per-lane global source pre-swizzled (rule 21).
// ROUND-3 CHANGE: ONE barrier per K-step, NO inline lgkmcnt. Compiler emits counted
// lgkmcnt between ds_read and dependent MFMA (m97 evidence) -> LDS port time overlaps
// MFMA instead of strictly alternating (prior 4-barrier lockstep = 2900cy/K-step measured,
// LDS 1530cy + MFMA 310cy serialized + drains).
// Safety: every ds_read feeds an MFMA issued before the closing barrier => all reads of
// ring R complete before that barrier => restaging R at iter i+1 (after barrier) is WAR-safe.
// vmcnt ledger: stage 4 loads/iter, 12 outstanding steady-state; VM8 at iter i retires the
// 4 loads of K-step i+1 (FIFO) before the barrier releases iter i+1's reads.
#define VM8 asm volatile("s_waitcnt vmcnt(8)" ::: "memory")
#define VM4 asm volatile("s_waitcnt vmcnt(4)" ::: "memory")
#define VM0 asm volatile("s_waitcnt vmcnt(0)" ::: "memory")
#define VMNONE ((void)0)

#define STAGE_A(S, R2)                       \
    do {                                     \
        u16* Ld = &sbuf[(R2) * 16384];       \
        long ko = (long)(S) * 32;            \
        g2lds16(pA0 + ko, Ld + dA0);         \
        g2lds16(pA1 + ko, Ld + dA1);         \
    } while (0)
#define STAGE_B(S, R2)                          \
    do {                                        \
        u16* Ld = &sbuf[(R2) * 16384 + 8192];   \
        long ko = (long)(S) * 32;               \
        g2lds16(pB0 + ko, Ld + dA0);            \
        g2lds16(pB1 + ko, Ld + dA1);            \
    } while (0)

#define MQUAD(RB, AV)                          \
    acc[RB][0] = MFMA16(AV, b0, acc[RB][0]);   \
    acc[RB][1] = MFMA16(AV, b1, acc[RB][1]);   \
    acc[RB][2] = MFMA16(AV, b2, acc[RB][2]);   \
    acc[RB][3] = MFMA16(AV, b3, acc[RB][3]);

#define GITER(RING, S3, STG, VMSTMT)                                        \
    {                                                                       \
        const u16* LA = &sbuf[(RING) * 16384 + wm8 * 512 + lane8];          \
        const u16* LB = &sbuf[(RING) * 16384 + 8192 + wn4 * 512 + lane8];   \
        bf16x8 b0 = *(const bf16x8*)&LB[0];                                 \
        bf16x8 b1 = *(const bf16x8*)&LB[512];                               \
        bf16x8 b2 = *(const bf16x8*)&LB[1024];                              \
        bf16x8 b3 = *(const bf16x8*)&LB[1536];                              \
        bf16x8 a0 = *(const bf16x8*)&LA[0];                                 \
        bf16x8 a1 = *(const bf16x8*)&LA[512];                               \
        bf16x8 a2 = *(const bf16x8*)&LA[1024];                              \
        bf16x8 a3 = *(const bf16x8*)&LA[1536];                              \
        bf16x8 a4 = *(const bf16x8*)&LA[2048];                              \
        bf16x8 a5 = *(const bf16x8*)&LA[2560];                              \
        bf16x8 a6 = *(const bf16x8*)&LA[3072];                              \
        bf16x8 a7 = *(const bf16x8*)&LA[3584];                              \
        if (STG) {                                                          \
            STAGE_A(S3, ((RING) + 3) & 3);                                  \
            STAGE_B(S3, ((RING) + 3) & 3);                                  \
        }                                                                   \
        __builtin_amdgcn_s_setprio(1);                                      \
        MQUAD(0, a0)                                                        \
        MQUAD(1, a1)                                                        \
        MQUAD(2, a2)                                                        \
        MQUAD(3, a3)                                                        \
        MQUAD(4, a4)                                                        \
        MQUAD(5, a5)                                                        \
        MQUAD(6, a6)                                                        \
        MQUAD(7, a7)                                                        \
        __builtin_amdgcn_s_setprio(0);                                      \
        VMSTMT;                                                             \
        __builtin_amdgcn_s_barrier();                                       \
        __builtin_amdgcn_sched_barrier(0);                                  \
    }

__global__ __launch_bounds__(512, 2) void gemm256(const u16* __restrict__ A,
                                                  const u16* __restrict__ B,
                                                  u16* __restrict__ Cq, u16* __restrict__ Cz) {
    __shared__ __align__(16) u16 sbuf[65536];  // 128 KiB: 4 rings x (A 8192 + B 8192 u16)
    int bid = blockIdx.x;
    int swz = (bid & 7) * 96 + (bid >> 3);  // bijective XCD swizzle, 768 = 8*96
    int m0 = (swz & 15) * 256;              // M=4096 -> 16 m-tiles (fastest: share B panel)
    int n0 = (swz >> 4) * 256;              // N=12288 -> 48 n-tiles
    int tid = threadIdx.x;
    int lane = tid & 63, w = tid >> 6;
    int l15 = lane & 15, quad = lane >> 4;
    int wm8 = (w >> 2) * 8, wn4 = (w & 3) * 4;
    int lane8 = lane * 8;
    // staging: wave w covers fragments w (j=0) and 8+w (j=1) of each operand
    int dA0 = w * 512 + lane8, dA1 = w * 512 + lane8 + 4096;
    const u16* pA0 = &A[(long)(m0 + w * 16 + l15) * 2048 + quad * 8];
    const u16* pA1 = pA0 + 128L * 2048;
    const u16* pB0 = &B[(long)(n0 + w * 16 + l15) * 2048 + quad * 8];
    const u16* pB1 = pB0 + 128L * 2048;

    f32x4 acc[8][4];
#pragma unroll
    for (int i = 0; i < 8; i++)
#pragma unroll
        for (int j = 0; j < 4; j++) acc[i][j] = (f32x4){0.f, 0.f, 0.f, 0.f};

    // prologue: stage K-steps 0,1,2 (12 loads); wait until K-step 0 landed (8 outstanding)
    STAGE_A(0, 0);
    STAGE_B(0, 0);
    STAGE_A(1, 1);
    STAGE_B(1, 1);
    STAGE_A(2, 2);
    STAGE_B(2, 2);
    VM8;
    __builtin_amdgcn_s_barrier();
    __builtin_amdgcn_sched_barrier(0);

    for (int it = 0; it < 60; it += 4) {
        GITER(0, it + 3, 1, VM8);
        GITER(1, it + 4, 1, VM8);
        GITER(2, it + 5, 1, VM8);
        GITER(3, it + 6, 1, VM8);
    }
    GITER(0, 63, 1, VM8);   // i=60
    GITER(1, 0, 0, VM4);    // i=61: outstanding {62,63}=8, retire 62
    GITER(2, 0, 0, VM0);    // i=62: retire 63
    GITER(3, 0, 0, VMNONE); // i=63

    // epilogue: acc -> LDS bf16 [256][256] with 32B-granule XOR swizzle, then coalesced store
#pragma unroll
    for (int rb = 0; rb < 8; rb++)
#pragma unroll
        for (int cb = 0; cb < 4; cb++)
#pragma unroll
            for (int r = 0; r < 4; r++) {
                int row = wm8 * 16 + rb * 16 + quad * 4 + r;
                int col = wn4 * 16 + cb * 16 + l15;
                int cg = col >> 4;
                int phys = row * 256 + ((cg ^ (row & 7)) << 4) + (col & 15);
                sbuf[phys] = f2bf(acc[rb][cb][r]);
            }
    __syncthreads();
    u16* dst;
    long dldc;
    int ncol0;
    if (n0 >= 8192) {
        dst = Cz;
        dldc = 4096;
        ncol0 = n0 - 8192;
    } else {
        dst = Cq;
        dldc = 8192;
        ncol0 = n0;
    }
#pragma unroll
    for (int p = 0; p < 16; p++) {
        int row = p * 16 + (tid >> 5);
        int seg = tid & 31;
        int cg = seg >> 1;
        int phys = row * 256 + ((cg ^ (row & 7)) << 4) + (seg & 1) * 8;
        *(uint4*)&dst[(long)(m0 + row) * dldc + ncol0 + seg * 8] = *(const uint4*)&sbuf[phys];
    }
}

// ---------------- ba = hidden @ W_ba -> g, beta (MFMA, padded LDS) ----------------
__global__ __launch_bounds__(256) void ba_gemm(const u16* __restrict__ hid,
                                               const u16* __restrict__ WbaT,
                                               const float* __restrict__ A_log,
                                               const float* __restrict__ dt_bias,
                                               float* __restrict__ g, float* __restrict__ beta) {
    __shared__ __align__(16) u16 As2[32 * 40];
    __shared__ __align__(16) u16 Bs2[64 * 40];
    int m0 = blockIdx.x * 32;
    int tid = threadIdx.x, lane = tid & 63, w = tid >> 6;
    int quad = lane >> 4, l15 = lane & 15;
    int trow = w & 1;
    int ctile = (w >> 1) * 2;
    f32x4 acc[2];
    acc[0] = (f32x4){0.f, 0.f, 0.f, 0.f};
    acc[1] = (f32x4){0.f, 0.f, 0.f, 0.f};
    int srow = tid >> 2, sc8 = (tid & 3) * 8;
    for (int k0 = 0; k0 < 2048; k0 += 32) {
        if (tid < 128)
            *(uint4*)&As2[srow * 40 + sc8] =
                *(const uint4*)&hid[(long)(m0 + srow) * 2048 + k0 + sc8];
        *(uint4*)&Bs2[srow * 40 + sc8] = *(const uint4*)&WbaT[(long)srow * 2048 + k0 + sc8];
        __syncthreads();
        bf16x8 a = *(const bf16x8*)&As2[(trow * 16 + l15) * 40 + quad * 8];
#pragma unroll
        for (int j = 0; j < 2; j++) {
            bf16x8 b = *(const bf16x8*)&Bs2[((ctile + j) * 16 + l15) * 40 + quad * 8];
            acc[j] = MFMA16(a, b, acc[j]);
        }
        __syncthreads();
    }
#pragma unroll
    for (int j = 0; j < 2; j++)
#pragma unroll
        for (int r = 0; r < 4; r++) {
            int tok = m0 + trow * 16 + quad * 4 + r;
            int col = (ctile + j) * 16 + l15;
            float tot = acc[j][r];
            if (col < 32) {
                beta[(long)tok * 32 + col] = 1.f / (1.f + expf(-tot));
            } else {
                int h = col - 32;
                float x = tot + dt_bias[h];
                float sp = (x > 20.f) ? x : log1pf(expf(x));
                g[(long)tok * 32 + h] = -expf(A_log[h]) * sp;
            }
        }
}

// ---------------- causal conv + SiLU + l2norm + split (coalesced, LDS) ----------------
__global__ __launch_bounds__(256) void conv_gate(const u16* __restrict__ qkv,
                                                 const float* __restrict__ conv_w,
                                                 u16* __restrict__ qn, u16* __restrict__ kn,
                                                 u16* __restrict__ vc) {
    int tok = blockIdx.x, tid = threadIdx.x;
    int tloc = tok & (T_SEQ - 1);
    __shared__ float mixed[8192];
    __shared__ float sh_norm[32];
    uint4 zero4;
    zero4.x = zero4.y = zero4.z = zero4.w = 0u;
#pragma unroll
    for (int i = 0; i < 4; i++) {
        int c = (i * 256 + tid) * 8;
        long base = (long)tok * 8192 + c;
        uint4 x3 = *(const uint4*)&qkv[base];
        uint4 x2 = (tloc >= 1) ? *(const uint4*)&qkv[base - 8192] : zero4;
        uint4 x1 = (tloc >= 2) ? *(const uint4*)&qkv[base - 16384] : zero4;
        uint4 x0 = (tloc >= 3) ? *(const uint4*)&qkv[base - 24576] : zero4;
        const u16* p0 = (const u16*)&x0;
        const u16* p1 = (const u16*)&x1;
        const u16* p2 = (const u16*)&x2;
        const u16* p3 = (const u16*)&x3;
#pragma unroll
        for (int e = 0; e < 8; e++) {
            float4 wv = *(const float4*)&conv_w[(long)(c + e) * 4];
            float a = bf2f(p0[e]) * wv.x + bf2f(p1[e]) * wv.y + bf2f(p2[e]) * wv.z +
                      bf2f(p3[e]) * wv.w;
            mixed[c + e] = a / (1.f + __expf(-a));
        }
    }
    __syncthreads();
    int grp = tid >> 3, sub = tid & 7;
    float ss = 0.f;
#pragma unroll
    for (int e = 0; e < 16; e++) {
        float v = mixed[grp * 128 + sub * 16 + e];
        ss += v * v;
    }
    ss += __shfl_xor(ss, 4, 8);
    ss += __shfl_xor(ss, 2, 8);
    ss += __shfl_xor(ss, 1, 8);
    if (sub == 0) sh_norm[grp] = rsqrtf(ss + 1e-6f);
    __syncthreads();
#pragma unroll
    for (int i = 0; i < 4; i++) {
        int c = (i * 256 + tid) * 8;
        float nf = (c < 2048) ? sh_norm[c >> 7] * 0.08838834764831845f
                              : ((c < 4096) ? sh_norm[c >> 7] : 1.f);
        u16 ob[8];
#pragma unroll
        for (int e = 0; e < 8; e++) ob[e] = f2bf(mixed[c + e] * nf);
        uint4 val = *(uint4*)ob;
        if (c < 2048)
            *(uint4*)&qn[(long)tok * 2048 + c] = val;
        else if (c < 4096)
            *(uint4*)&kn[(long)tok * 2048 + (c - 2048)] = val;
        else
            *(uint4*)&vc[(long)tok * 4096 + (c - 4096)] = val;
    }
}

// ---------------- phase A: per-chunk WY transform (padded LDS, YT transposed) ----------
__global__ __launch_bounds__(256) void phaseA(const u16* __restrict__ qn,
                                              const u16* __restrict__ kn,
                                              const u16* __restrict__ vc,
                                              const float* __restrict__ g,
                                              const float* __restrict__ beta,
                                              u16* __restrict__ Tv_g, u16* __restrict__ Tw_g,
                                              u16* __restrict__ Q2_g, u16* __restrict__ obuf) {
    __shared__ __align__(16) u16 kbuf[64][136];  // k tile (padded); later L at stride 72
    __shared__ __align__(16) float BMt[64][68];  // BMt[j][i] (padded)
    __shared__ __align__(16) u16 YT[256][72];    // Y^T: row=col(0..127 V / 128..255 W), col=token
    u16* Lbf = &kbuf[0][0];

    int bid = blockIdx.x;
    int c = bid & 31, h = (bid >> 5) & 31, b = bid >> 10;
    int hk = h >> 1;
    long tokbase = (long)b * T_SEQ + c * 64;
    long cb = (long)bid * 8192;
    int tid = threadIdx.x, lane = tid & 63, w = tid >> 6;
    int quad = lane >> 4, l15 = lane & 15;

    float gl = g[(tokbase + lane) * 32 + h];
    float bl = beta[(tokbase + lane) * 32 + h];
    float cgl = gl;
#pragma unroll
    for (int d = 1; d < 64; d <<= 1) {
        float y = __shfl_up(cgl, d);
        if (lane >= d) cgl += y;
    }
    float wscl = bl * __expf(cgl);
    float eCgl = __expf(cgl);

#pragma unroll
    for (int p = 0; p < 4; p++) {
        int u = p * 256 + tid;
        int row = u >> 4, col8 = (u & 15) * 8;
        *(uint4*)&kbuf[row][col8] = *(const uint4*)&kn[(tokbase + row) * 2048 + hk * 128 + col8];
    }
    __syncthreads();

    // Gram_kk -> BMt
    {
        f32x4 gk[4];
#pragma unroll
        for (int nj = 0; nj < 4; nj++) gk[nj] = (f32x4){0.f, 0.f, 0.f, 0.f};
#pragma unroll
        for (int kk = 0; kk < 4; kk++) {
            bf16x8 a = *(const bf16x8*)&kbuf[w * 16 + l15][kk * 32 + quad * 8];
#pragma unroll
            for (int nj = 0; nj < 4; nj++) {
                bf16x8 bb = *(const bf16x8*)&kbuf[nj * 16 + l15][kk * 32 + quad * 8];
                gk[nj] = MFMA16(a, bb, gk[nj]);
            }
        }
#pragma unroll
        for (int nj = 0; nj < 4; nj++)
#pragma unroll
            for (int r = 0; r < 4; r++) {
                int i = w * 16 + quad * 4 + r;
                int j = nj * 16 + l15;
                float cgi = __shfl(cgl, i), cgj = __shfl(cgl, j);
                float bi = __shfl(bl, i);
                BMt[j][i] = (j < i) ? bi * gk[nj][r] * __expf(cgi - cgj) : 0.f;
            }
    }
    __syncthreads();

    // blocked forward substitution: (I+BM) Y = B*[V | W] ; Y^T into YT
    {
        int col = tid;
        bool isV = col < 128;
        int kcol = col & 127;
        long vbase = tokbase * 4096 + h * 128 + kcol;
        float Yreg[8], acc8[8];
#pragma unroll 1
        for (int bi = 0; bi < 8; ++bi) {
            float vr[8];
            if (isV) {
#pragma unroll
                for (int ii = 0; ii < 8; ii++)
                    vr[ii] = bf2f(vc[vbase + (long)(bi * 8 + ii) * 4096]);
            }
#pragma unroll
            for (int ii = 0; ii < 8; ii++) acc8[ii] = 0.f;
            for (int j = 0; j < bi * 8; ++j) {
                float yv = bf2f(YT[col][j]);
                float4 m0 = *(const float4*)&BMt[j][bi * 8];
                float4 m1 = *(const float4*)&BMt[j][bi * 8 + 4];
                acc8[0] += m0.x * yv;
                acc8[1] += m0.y * yv;
                acc8[2] += m0.z * yv;
                acc8[3] += m0.w * yv;
                acc8[4] += m1.x * yv;
                acc8[5] += m1.y * yv;
                acc8[6] += m1.z * yv;
                acc8[7] += m1.w * yv;
            }
            u16 outb[8];
#pragma unroll
            for (int ii = 0; ii < 8; ii++) {
                int i = bi * 8 + ii;
                float rhs = isV ? __shfl(bl, i) * vr[ii] : __shfl(wscl, i) * bf2f(kbuf[i][kcol]);
                float s = rhs - acc8[ii];
#pragma unroll
                for (int jj = 0; jj < 8; jj++)
                    if (jj < ii) s -= BMt[bi * 8 + jj][i] * Yreg[jj];
                Yreg[ii] = s;
                outb[ii] = f2bf(s);
            }
            *(uint4*)&YT[col][bi * 8] = *(uint4*)outb;
#pragma unroll
            for (int ii = 0; ii < 8; ii++) {
                if (isV)
                    Tv_g[cb + (bi * 8 + ii) * 128 + kcol] = outb[ii];
                else
                    Tw_g[cb + (bi * 8 + ii) * 128 + kcol] = outb[ii];
            }
        }
    }
    __syncthreads();

    // Gram_qk -> L (bf16, stride 72, overlays kbuf)
    {
        f32x4 qk_[4];
#pragma unroll
        for (int nj = 0; nj < 4; nj++) qk_[nj] = (f32x4){0.f, 0.f, 0.f, 0.f};
#pragma unroll
        for (int kk = 0; kk < 4; kk++) {
            bf16x8 a = *(const bf16x8*)&qn[(tokbase + w * 16 + l15) * 2048 + hk * 128 + kk * 32 +
                                           quad * 8];
#pragma unroll
            for (int nj = 0; nj < 4; nj++) {
                bf16x8 bb = *(const bf16x8*)&kbuf[nj * 16 + l15][kk * 32 + quad * 8];
                qk_[nj] = MFMA16(a, bb, qk_[nj]);
            }
        }
        __syncthreads();  // all kbuf reads done before Lbf overwrite
#pragma unroll
        for (int nj = 0; nj < 4; nj++)
#pragma unroll
            for (int r = 0; r < 4; r++) {
                int t = w * 16 + quad * 4 + r;
                int rr = nj * 16 + l15;
                float cgt = __shfl(cgl, t), cgr = __shfl(cgl, rr);
                float val = (rr <= t) ? qk_[nj][r] * __expf(cgt - cgr) : 0.f;
                Lbf[t * 72 + rr] = f2bf(val);
            }
    }
    __syncthreads();

    // O_loc = L*Tv -> obuf ; Q2 = Qtilde - L*Tw   (A=Lbf b128, B=YT b128)
#pragma unroll 1
    for (int half = 0; half < 2; half++) {
        f32x4 oa[8];
#pragma unroll
        for (int nj = 0; nj < 8; nj++) oa[nj] = (f32x4){0.f, 0.f, 0.f, 0.f};
#pragma unroll
        for (int kk = 0; kk < 2; kk++) {
            bf16x8 a = *(const bf16x8*)&Lbf[(w * 16 + l15) * 72 + kk * 32 + quad * 8];
#pragma unroll
            for (int nj = 0; nj < 8; nj++) {
                bf16x8 bb = *(const bf16x8*)&YT[half * 128 + nj * 16 + l15][kk * 32 + quad * 8];
                oa[nj] = MFMA16(a, bb, oa[nj]);
            }
        }
        if (half == 0) {
#pragma unroll
            for (int nj = 0; nj < 8; nj++)
#pragma unroll
                for (int r = 0; r < 4; r++) {
                    int t = w * 16 + quad * 4 + r;
                    int vcol = nj * 16 + l15;
                    obuf[(tokbase + t) * 4096 + h * 128 + vcol] = f2bf(oa[nj][r]);
                }
        } else {
#pragma unroll
            for (int nj = 0; nj < 8; nj++)
#pragma unroll
                for (int r = 0; r < 4; r++) {
                    int t = w * 16 + quad * 4 + r;
                    int kcol = nj * 16 + l15;
                    float qsc = __shfl(eCgl, t);
                    float qv = bf2f(qn[(tokbase + t) * 2048 + hk * 128 + kcol]);
                    Q2_g[cb + t * 128 + kcol] = f2bf(qsc * qv - oa[nj][r]);
                }
        }
    }
}

// ---------------- phase B: sequential chunk recurrence, software-pipelined ----------------
__global__ __launch_bounds__(256) void phaseB(const u16* __restrict__ kn,
                                              const float* __restrict__ g,
                                              const u16* __restrict__ Tv_g,
                                              const u16* __restrict__ Tw_g,
                                              const u16* __restrict__ Q2_g,
                                              u16* __restrict__ obuf) {
    __shared__ __align__(16) float Sf[128][32];
    __shared__ __align__(16) u16 SbfT[32][136];
    __shared__ __align__(16) u16 KhT[128][72];
    __shared__ __align__(16) u16 Ut[32][72];

    int bid = blockIdx.x;
    int vq = bid & 3, h = (bid >> 2) & 31, b = bid >> 7;
    int hk = h >> 1;
    int tid = threadIdx.x, lane = tid & 63, w = tid >> 6;
    int quad = lane >> 4, l15 = lane & 15;

    for (int p = tid; p < 128 * 32; p += 256) ((float*)Sf)[p] = 0.f;
    for (int p = tid; p < 32 * 136; p += 256) ((u16*)SbfT)[p] = 0;
    __syncthreads();

    float gl_pf;
    uint4 kreg[4];
    bf16x8 aTw[4], aQ2[4];
    u16 tvv_pf[2][4], oold[2][4];

#define PB_PREFETCH(cc)                                                                      \
    {                                                                                        \
        long tb_ = (long)b * T_SEQ + (cc) * 64;                                              \
        long cb_ = ((long)((b * 32 + h) * 32) + (cc)) * 8192;                                \
        gl_pf = g[(tb_ + lane) * 32 + h];                                                    \
        const u16* kp_ = &kn[(tb_ + lane) * 2048 + hk * 128 + w * 32];                       \
        kreg[0] = *(const uint4*)&kp_[0];                                                    \
        kreg[1] = *(const uint4*)&kp_[8];                                                    \
        kreg[2] = *(const uint4*)&kp_[16];                                                   \
        kreg[3] = *(const uint4*)&kp_[24];                                                   \
        _Pragma("unroll") for (int kk = 0; kk < 4; kk++) {                                   \
            aTw[kk] = *(const bf16x8*)&Tw_g[cb_ + (w * 16 + l15) * 128 + kk * 32 + quad * 8]; \
            aQ2[kk] = *(const bf16x8*)&Q2_g[cb_ + (w * 16 + l15) * 128 + kk * 32 + quad * 8]; \
        }                                                                                    \
        _Pragma("unroll") for (int nj = 0; nj < 2; nj++) _Pragma("unroll")                   \
            for (int r = 0; r < 4; r++) {                                                    \
            int i_ = w * 16 + quad * 4 + r;                                                  \
            int vg_ = vq * 32 + nj * 16 + l15;                                               \
            tvv_pf[nj][r] = Tv_g[cb_ + (long)i_ * 128 + vg_];                                \
            oold[nj][r] = obuf[(tb_ + i_) * 4096 + h * 128 + vg_];                           \
        }                                                                                    \
    }

    PB_PREFETCH(0);

    for (int c = 0; c < 32; ++c) {
        long tokbase = (long)b * T_SEQ + c * 64;
        float cgl = gl_pf;
#pragma unroll
        for (int d = 1; d < 64; d <<= 1) {
            float y = __shfl_up(cgl, d);
            if (lane >= d) cgl += y;
        }
        float cgC = __shfl(cgl, 63);
        float A_C = __expf(cgC);
        float kscl = __expf(cgC - cgl);

        {
            const u16* kk16 = (const u16*)kreg;
#pragma unroll
            for (int j = 0; j < 32; j++) KhT[w * 32 + j][lane] = f2bf(bf2f(kk16[j]) * kscl);
        }

        f32x4 y1[2], oo[2];
#pragma unroll
        for (int nj = 0; nj < 2; nj++) {
            y1[nj] = (f32x4){0.f, 0.f, 0.f, 0.f};
            oo[nj] = (f32x4){0.f, 0.f, 0.f, 0.f};
        }
#pragma unroll
        for (int kk = 0; kk < 4; kk++) {
#pragma unroll
            for (int nj = 0; nj < 2; nj++) {
                bf16x8 bb = *(const bf16x8*)&SbfT[nj * 16 + l15][kk * 32 + quad * 8];
                y1[nj] = MFMA16(aTw[kk], bb, y1[nj]);
                oo[nj] = MFMA16(aQ2[kk], bb, oo[nj]);
            }
        }
#pragma unroll
        for (int nj = 0; nj < 2; nj++)
#pragma unroll
            for (int r = 0; r < 4; r++) {
                int i = w * 16 + quad * 4 + r;
                int vl = nj * 16 + l15;
                int vg = vq * 32 + vl;
                Ut[vl][i] = f2bf(bf2f(tvv_pf[nj][r]) - y1[nj][r]);
                obuf[(tokbase + i) * 4096 + h * 128 + vg] = f2bf(bf2f(oold[nj][r]) + oo[nj][r]);
            }
        __syncthreads();

        if (c + 1 < 32) PB_PREFETCH(c + 1);

#pragma unroll
        for (int mm = 0; mm < 2; mm++) {
            int mi = 2 * w + mm;
#pragma unroll
            for (int nj = 0; nj < 2; nj++) {
                f32x4 sacc;
#pragma unroll
                for (int r = 0; r < 4; r++)
                    sacc[r] = A_C * Sf[mi * 16 + quad * 4 + r][nj * 16 + l15];
#pragma unroll
                for (int kk = 0; kk < 2; kk++) {
                    bf16x8 a = *(const bf16x8*)&KhT[mi * 16 + l15][kk * 32 + quad * 8];
                    bf16x8 bb = *(const bf16x8*)&Ut[nj * 16 + l15][kk * 32 + quad * 8];
                    sacc = MFMA16(a, bb, sacc);
                }
#pragma unroll
                for (int r = 0; r < 4; r++) {
                    int kd = mi * 16 + quad * 4 + r, vl = nj * 16 + l15;
                    Sf[kd][vl] = sacc[r];
                    SbfT[vl][kd] = f2bf(sacc[r]);
                }
            }
        }
        __syncthreads();
    }
#undef PB_PREFETCH
}

// ---------------- gated RMSNorm ----------------
__global__ __launch_bounds__(256) void gated_norm(const u16* __restrict__ obuf,
                                                  const u16* __restrict__ zbuf,
                                                  const float* __restrict__ norm_w,
                                                  u16* __restrict__ xn) {
    int tok = blockIdx.x, tid = threadIdx.x;
    long obase = (long)tok * 4096 + tid * 16;
    u16 ob[16], zb[16];
    *(uint4*)(ob + 0) = *(const uint4*)&obuf[obase];
    *(uint4*)(ob + 8) = *(const uint4*)&obuf[obase + 8];
    *(uint4*)(zb + 0) = *(const uint4*)&zbuf[obase];
    *(uint4*)(zb + 8) = *(const uint4*)&zbuf[obase + 8];
    float x[16];
    float ss = 0.f;
#pragma unroll
    for (int i = 0; i < 16; i++) {
        float ov = bf2f(ob[i]);
        float zv = bf2f(zb[i]);
        float xv = ov * (zv / (1.f + expf(-zv)));
        x[i] = xv;
        ss += xv * xv;
    }
    ss += __shfl_xor(ss, 4, 8);
    ss += __shfl_xor(ss, 2, 8);
    ss += __shfl_xor(ss, 1, 8);
    float scale = rsqrtf(ss * (1.f / 128.f) + 1e-6f);
    int cbase = (tid * 16) & 127;
#pragma unroll
    for (int i = 0; i < 16; i++)
        xn[(long)tok * 4096 + tid * 16 + i] = f2bf(x[i] * scale * (1.f + norm_w[cbase + i]));
}

// ---------------- launch ----------------
extern "C" void kernel_launch(void* const* d_in, const int* in_sizes, int n_in, void* d_out,
                              int out_size, void* d_ws, size_t ws_size, hipStream_t stream) {
    const float* hidden = (const float*)d_in[0];
    const float* W_qkvz = (const float*)d_in[1];
    const float* W_ba = (const float*)d_in[2];
    const float* conv_w = (const float*)d_in[3];
    const float* A_log = (const float*)d_in[4];
    const float* dt_bias = (const float*)d_in[5];
    const float* norm_w = (const float*)d_in[6];
    const float* W_out = (const float*)d_in[7];
    float* out = (float*)d_out;

    char* ws = (char*)d_ws;
    u16* wqT = (u16*)(ws + 0);
    u16* qn = (u16*)(ws + 0);
    u16* vc = (u16*)(ws + 16777216L);
    u16* hidbf = (u16*)(ws + 50331648L);
    u16* kn = (u16*)(ws + 50331648L);
    u16* woT = (u16*)(ws + 67108864L);
    u16* qkv_raw = (u16*)(ws + 83886080L);
    u16* Tv = (u16*)(ws + 83886080L);
    u16* Tw = (u16*)(ws + 117440512L);
    u16* xn = (u16*)(ws + 83886080L);
    u16* WbaT = (u16*)(ws + 150994944L);
    u16* zbuf = (u16*)(ws + 150994944L);
    u16* Q2 = (u16*)(ws + 184549376L);
    float* g = (float*)(ws + 218103808L);
    float* beta = (float*)(ws + 218628096L);
    u16* obuf = vc;

    cast_f32_bf16<<<8192, 256, 0, stream>>>(hidden, hidbf, 8388608L);
    transpose_cast<<<dim3(384, 64), 256, 0, stream>>>(W_qkvz, wqT, 2048, 12288);
    transpose_cast<<<dim3(64, 128), 256, 0, stream>>>(W_out, woT, 4096, 2048);
    transpose_cast<<<dim3(2, 64), 256, 0, stream>>>(W_ba, WbaT, 2048, 64);
    ba_gemm<<<128, 256, 0, stream>>>(hidbf, WbaT, A_log, dt_bias, g, beta);
    gemm256<<<768, 512, 0, stream>>>(hidbf, wqT, qkv_raw, zbuf);
    conv_gate<<<4096, 256, 0, stream>>>(qkv_raw, conv_w, qn, kn, vc);
    phaseA<<<2048, 256, 0, stream>>>(qn, kn, vc, g, beta, Tv, Tw, Q2, obuf);
    phaseB<<<256, 256, 0, stream>>>(kn, g, Tv, Tw, Q2, obuf);
    gated_norm<<<4096, 256, 0, stream>>>(obuf, zbuf, norm_w, xn);
    gemm_bt<0><<<dim3(32, 16), 256, 0, stream>>>(xn, woT, out, nullptr, 4096, 2048, 4096, 4096,
                                                 4096, 2048);
}